// Round 4
// baseline (114.291 us; speedup 1.0000x reference)
//
#include <hip/hip_runtime.h>
#include <math.h>

#define B_ 32
#define D_ 16
#define T_ 1024
#define P_ 64
#define L_ 32
#define KB 524288.0f       // 2^19 bias: prefmin(e) = KB - prefmax(KB - e)

typedef short short8 __attribute__((ext_vector_type(8)));
typedef float f32x4 __attribute__((ext_vector_type(4)));
typedef unsigned short ushort_t;

// ---- DPP helpers -----------------------------------------------------------
template<int CTRL, int ROW_MASK, bool BC>
__device__ __forceinline__ float dpp_mov(float old_, float src) {
  int o = __builtin_bit_cast(int, old_);
  int s = __builtin_bit_cast(int, src);
  int r = __builtin_amdgcn_update_dpp(o, s, CTRL, ROW_MASK, 0xf, BC);
  return __builtin_bit_cast(float, r);
}

// Inclusive prefix-sum over each 32-lane half (0-fill -> fused v_add_f32_dpp).
__device__ __forceinline__ float scan_sum32(float v) {
  v += dpp_mov<0x111, 0xf, true>(0.f, v);   // row_shr:1
  v += dpp_mov<0x112, 0xf, true>(0.f, v);   // row_shr:2
  v += dpp_mov<0x114, 0xf, true>(0.f, v);   // row_shr:4
  v += dpp_mov<0x118, 0xf, true>(0.f, v);   // row_shr:8
  v += dpp_mov<0x142, 0xa, false>(0.f, v);  // row_bcast15 -> rows 1,3
  return v;
}

// DUAL inclusive prefix-MAX over each 32-lane half: two independent chains
// interleaved in one asm block. Chain B's dpp fills chain A's 2-wait-state
// VALU->DPP hazard window (plus s_nop 0 safety margin): ~5 nop cycles per
// TWO columns vs ~10 per one in the single-chain version.
__device__ __forceinline__ void scan_max32_x2(float& u, float& v) {
  asm("s_nop 1\n\t"
      "v_max_f32_dpp %0, %0, %0 row_shr:1 row_mask:0xf bank_mask:0xf\n\t"
      "v_max_f32_dpp %1, %1, %1 row_shr:1 row_mask:0xf bank_mask:0xf\n\t"
      "s_nop 0\n\t"
      "v_max_f32_dpp %0, %0, %0 row_shr:2 row_mask:0xf bank_mask:0xf\n\t"
      "v_max_f32_dpp %1, %1, %1 row_shr:2 row_mask:0xf bank_mask:0xf\n\t"
      "s_nop 0\n\t"
      "v_max_f32_dpp %0, %0, %0 row_shr:4 row_mask:0xf bank_mask:0xf\n\t"
      "v_max_f32_dpp %1, %1, %1 row_shr:4 row_mask:0xf bank_mask:0xf\n\t"
      "s_nop 0\n\t"
      "v_max_f32_dpp %0, %0, %0 row_shr:8 row_mask:0xf bank_mask:0xf\n\t"
      "v_max_f32_dpp %1, %1, %1 row_shr:8 row_mask:0xf bank_mask:0xf\n\t"
      "s_nop 0\n\t"
      "v_max_f32_dpp %0, %0, %0 row_bcast:15 row_mask:0xa bank_mask:0xf\n\t"
      "v_max_f32_dpp %1, %1, %1 row_bcast:15 row_mask:0xa bank_mask:0xf"
      : "+v"(u), "+v"(v));
}

__device__ __forceinline__ ushort_t f2bf(float f) {   // fp32 -> bf16 RNE
  unsigned u = __builtin_bit_cast(unsigned, f);
  return (ushort_t)((u + 0x7FFFu + ((u >> 16) & 1u)) >> 16);
}
__device__ __forceinline__ float bf2f(ushort_t h) {
  unsigned u = ((unsigned)h) << 16;
  return __builtin_bit_cast(float, u);
}

// ---- fused prep: blocks 0..127 do prep_x, blocks 128..143 do prep_patt x4 --
__global__ __launch_bounds__(256) void prep_fused(
    const float* __restrict__ x, const float* __restrict__ patts,
    ushort_t* __restrict__ xA, ushort_t* __restrict__ pB) {
  const int bid = blockIdx.x;
  if (bid < 128) {
    int gid = bid * 256 + threadIdx.x;      // < 32768 = B_*T_
    int b = gid >> 10, t = gid & 1023;
    float x2 = 0.f;
    ushort_t o[32];
#pragma unroll
    for (int d = 0; d < 16; ++d) {
      float v = x[((b * 16 + d) << 10) + t];   // coalesced over t
      x2 = fmaf(v, v, x2);
      o[d] = f2bf(v);
    }
    o[16] = 0x3F80; o[17] = 0x3F80;            // bf16(1.0)
    ushort_t hi = f2bf(x2);
    o[18] = hi;
    o[19] = f2bf(x2 - bf2f(hi));               // hi/lo split
#pragma unroll
    for (int d = 20; d < 32; ++d) o[d] = 0;
    uint4* dst = (uint4*)(xA + (size_t)gid * 32);
#pragma unroll
    for (int q = 0; q < 4; ++q) {
      const ushort_t* s = o + q * 8;
      uint4 u;
      u.x = (unsigned)s[0] | ((unsigned)s[1] << 16);
      u.y = (unsigned)s[2] | ((unsigned)s[3] << 16);
      u.z = (unsigned)s[4] | ((unsigned)s[5] << 16);
      u.w = (unsigned)s[6] | ((unsigned)s[7] << 16);
      dst[q] = u;
    }
  } else {
    __shared__ float Ls[4][16 * 33];
    __shared__ float Lh[4][64];
    __shared__ float LP2[4][32];
    const int sub = threadIdx.x >> 6;
    const int l = threadIdx.x & 63;
    const int p = (bid - 128) * 4 + sub;
    const int half = l >> 5;
    const int m = l & 31;

    float p2acc = 0.f;
#pragma unroll
    for (int dd = 0; dd < 16; dd += 2) {
      int d = dd + half;                       // half 0: even d, half 1: odd d
      float v = patts[((p * 16 + d) << 5) + m];
      p2acc = fmaf(v, v, p2acc);
      Ls[sub][d * 33 + m] = scan_sum32(v);     // prefix over m (per half)
    }
    Lh[sub][l] = p2acc;
    __syncthreads();
    {
      float tot = Lh[sub][m] + Lh[sub][32 + m];
      float pref = scan_sum32(tot);
      if (half == 0) LP2[sub][m] = pref;
    }
    __syncthreads();

    const int n = l & 15, q = l >> 4;
#pragma unroll
    for (int iblk = 0; iblk < 2; ++iblk) {
      const int i = iblk * 16 + n;
      ushort_t o[8];
      if (q < 2) {
#pragma unroll
        for (int e = 0; e < 8; ++e)
          o[e] = f2bf(-2.f * Ls[sub][(q * 8 + e) * 33 + i]);
      } else if (q == 2) {
        float P2 = LP2[sub][i];
        ushort_t hi = f2bf(P2);
        o[0] = hi; o[1] = f2bf(P2 - bf2f(hi));
        o[2] = f2bf((float)(i + 1)); o[3] = o[2];
        o[4] = o[5] = o[6] = o[7] = 0;
      } else {
#pragma unroll
        for (int e = 0; e < 8; ++e) o[e] = 0;
      }
      uint4 u;
      u.x = (unsigned)o[0] | ((unsigned)o[1] << 16);
      u.y = (unsigned)o[2] | ((unsigned)o[3] << 16);
      u.z = (unsigned)o[4] | ((unsigned)o[5] << 16);
      u.w = (unsigned)o[6] | ((unsigned)o[7] << 16);
      ((uint4*)pB)[(p * 2 + iblk) * 64 + l] = u;
    }
  }
}

// ---- main kernel -----------------------------------------------------------
// R4: DUAL problem interleave per wave (in-wave ILP replaces TLP).
//  * Each wave runs TWO independent DP chains: pattern pairs (pA0,pA0+1)
//    and (pA0+2,pA0+3), same b, same tiles. A-fragment (x data) is SHARED:
//    one global load feeds 8 MFMAs. Loop/addressing overhead amortized 2x.
//  * Chains interleaved instruction-by-instruction; dual fused scan cuts
//    DPP hazard nops from ~12 cyc/col to ~5 cyc per col-PAIR, and chain B
//    issues inside chain A's dependency latency (and vice versa).
//  * Grid 32b x 4 pgroups x 4 chunks = 512 blocks = exactly 2 blocks/CU,
//    4-wave blocks (R3's known-good shape). LDS 42.2KB/block -> 2/CU fits.
//  * Chunks unchanged: S0=12*ch, 28 tiles, 16-tile warm-up (numerics
//    identical to R3 -> absmax 0.25).
__global__ __launch_bounds__(256, 2) void dtw_kernel(
    const ushort_t* __restrict__ xA,    // [B][T][32 bf16]
    const ushort_t* __restrict__ pBg,   // [P][2][64][8 bf16]
    const float* __restrict__ wp,
    float* __restrict__ out)            // [B][P][T]
{
  __shared__ float lds[4 * 2640];   // 4 waves * 2 problems * [pad20+640]*2

  const int tid = threadIdx.x;
  const int l   = tid & 63;
  const int wid = tid >> 6;
  const int li  = l & 31;
  const int g   = l >> 5;
  const int q4  = l >> 4;
  const unsigned bx = blockIdx.x;
  const int ch   = bx & 3u;
  const unsigned rest = bx >> 2;           // [0,128)
  const int b     = rest >> 2;             // [0,32)
  const int pbase = (rest & 3) << 4;       // 16 patterns per block
  const int pA0   = pbase + (wid << 2);    // this wave: patterns pA0..pA0+3
  const float w = wp[0];
  const float nw = -w;
  const bool l0c = (li == 0), l31 = (li == 31);

  // uniform chunks: start 12*ch, 28 tiles each, 16-tile (256-col) warm-up
  const int S0    = ch * 12;
  const int nT    = 28;
  const int warmT = ch ? 16 : 0;

  // B fragments: 2 problems x 2 patterns x 2 iblks (register-resident)
  const short8* pBs = (const short8*)pBg;
  short8 B00 = pBs[((pA0    ) * 2 + 0) * 64 + l];
  short8 B01 = pBs[((pA0    ) * 2 + 1) * 64 + l];
  short8 B10 = pBs[((pA0 + 1) * 2 + 0) * 64 + l];
  short8 B11 = pBs[((pA0 + 1) * 2 + 1) * 64 + l];
  short8 B20 = pBs[((pA0 + 2) * 2 + 0) * 64 + l];
  short8 B21 = pBs[((pA0 + 2) * 2 + 1) * 64 + l];
  short8 B30 = pBs[((pA0 + 3) * 2 + 0) * 64 + l];
  short8 B31 = pBs[((pA0 + 3) * 2 + 1) * 64 + l];

  const short8* xAs = (const short8*)xA + ((size_t)b << 12);

  short8 Aa;
  auto loadA = [&](int t) {   // t local; global tile = S0 + t; SHARED by A&B
    Aa = xAs[((((S0 + t) << 4) + (l & 15)) << 2) + q4];
  };

  // layout per wave: problem A at [0,1320), problem B at [1320,2640);
  // each problem: [pad 20][pat0 640][pad 20][pat1 640]
  float* base = lds + wid * 2640;
  float* ldsW = base + 20 + (l & 15) * 20 + q4 * 4;
  const float* ldsRA  = base + 20 + g * 660 + li * 20;   // problem A, Z row li
  const float* ldsRxA = ldsRA - 20;                      // row li-1
  const float* ldsRB  = ldsRA + 1320;                    // problem B
  const float* ldsRxB = ldsRB - 20;

  // pad rows hold KB (Zx for row 0 = KB <=> Sx = 0); never overwritten
  if (l < 20) {
    base[l] = KB; base[660 + l] = KB; base[1320 + l] = KB; base[1980 + l] = KB;
  }
  __syncthreads();

  const f32x4 zk = {KB, KB, KB, KB};    // MFMA C operand: Z = S + KB

  auto fill = [&]() {
    f32x4 d0 = __builtin_amdgcn_mfma_f32_16x16x32_bf16(Aa, B00, zk, 0, 0, 0);
    f32x4 d1 = __builtin_amdgcn_mfma_f32_16x16x32_bf16(Aa, B01, zk, 0, 0, 0);
    f32x4 d2 = __builtin_amdgcn_mfma_f32_16x16x32_bf16(Aa, B10, zk, 0, 0, 0);
    f32x4 d3 = __builtin_amdgcn_mfma_f32_16x16x32_bf16(Aa, B11, zk, 0, 0, 0);
    f32x4 d4 = __builtin_amdgcn_mfma_f32_16x16x32_bf16(Aa, B20, zk, 0, 0, 0);
    f32x4 d5 = __builtin_amdgcn_mfma_f32_16x16x32_bf16(Aa, B21, zk, 0, 0, 0);
    f32x4 d6 = __builtin_amdgcn_mfma_f32_16x16x32_bf16(Aa, B30, zk, 0, 0, 0);
    f32x4 d7 = __builtin_amdgcn_mfma_f32_16x16x32_bf16(Aa, B31, zk, 0, 0, 0);
    *(f32x4*)(ldsW + 0)    = d0;      // A pat0, i 0..15   ([i][j] stride 20)
    *(f32x4*)(ldsW + 320)  = d1;      // A pat0, i 16..31
    *(f32x4*)(ldsW + 660)  = d2;      // A pat1, i 0..15
    *(f32x4*)(ldsW + 980)  = d3;      // A pat1, i 16..31
    *(f32x4*)(ldsW + 1320) = d4;      // B pat0, i 0..15
    *(f32x4*)(ldsW + 1640) = d5;      // B pat0, i 16..31
    *(f32x4*)(ldsW + 1980) = d6;      // B pat1, i 0..15
    *(f32x4*)(ldsW + 2300) = d7;      // B pat1, i 16..31
  };

  float* orowA = out + (((size_t)(b * P_ + pA0 + g)) << 10) + (S0 << 4);
  float* orowB = orowA + (2 << 10);
  float dcurA = 0.f, dcurB = 0.f;

  loadA(0);
  fill();
  loadA(1);

  for (int t = 0; t < nT; ++t) {
    // --- DP reads for tile t (both problems), BEFORE fill(t+1) overwrites ---
    f32x4 sA0 = *(const f32x4*)(ldsRA  + 0);
    f32x4 xA0 = *(const f32x4*)(ldsRxA + 0);
    f32x4 sB0 = *(const f32x4*)(ldsRB  + 0);
    f32x4 xB0 = *(const f32x4*)(ldsRxB + 0);
    f32x4 sA1 = *(const f32x4*)(ldsRA  + 4);
    f32x4 xA1 = *(const f32x4*)(ldsRxA + 4);
    f32x4 sB1 = *(const f32x4*)(ldsRB  + 4);
    f32x4 xB1 = *(const f32x4*)(ldsRxB + 4);
    f32x4 sA2 = *(const f32x4*)(ldsRA  + 8);
    f32x4 xA2 = *(const f32x4*)(ldsRxA + 8);
    f32x4 sB2 = *(const f32x4*)(ldsRB  + 8);
    f32x4 xB2 = *(const f32x4*)(ldsRxB + 8);
    f32x4 sA3 = *(const f32x4*)(ldsRA  + 12);
    f32x4 xA3 = *(const f32x4*)(ldsRxA + 12);
    f32x4 sB3 = *(const f32x4*)(ldsRB  + 12);
    f32x4 xB3 = *(const f32x4*)(ldsRxB + 12);

    if (t + 1 < nT) fill();         // consumes Aa = frag(t+1), in-place
    if (t + 2 < nT) loadA(t + 2);

    const bool first = (t == 0);
    const bool store = (t >= warmT);

    float4 rA0, rA1, rA2, rA3, rB0, rB1, rB2, rB3;
#pragma unroll
    for (int k4 = 0; k4 < 4; ++k4) {
      f32x4 SqA = (k4 == 0) ? sA0 : (k4 == 1) ? sA1 : (k4 == 2) ? sA2 : sA3;
      f32x4 XqA = (k4 == 0) ? xA0 : (k4 == 1) ? xA1 : (k4 == 2) ? xA2 : xA3;
      f32x4 SqB = (k4 == 0) ? sB0 : (k4 == 1) ? sB1 : (k4 == 2) ? sB2 : sB3;
      f32x4 XqB = (k4 == 0) ? xB0 : (k4 == 1) ? xB1 : (k4 == 2) ? xB2 : xB3;
      float4 rvA, rvB;
#pragma unroll
      for (int e = 0; e < 4; ++e) {
        float ZoA = SqA[e], ZxA = XqA[e];
        float ZoB = SqB[e], ZxB = XqB[e];
        float aA = fmaf(nw, dcurA, ZxA);        // ZxA - w*dA
        float cA = fmaf(nw, dcurA, ZoA);        // ZA  - w*dA
        float aB = fmaf(nw, dcurB, ZxB);
        float cB = fmaf(nw, dcurB, ZoB);
        float uA, uB;
        // u = max(shr1(c), a) for both chains; lanes 0/32 fixed below
        asm("s_nop 1\n\t"
            "v_max_f32_dpp %0, %2, %3 wave_shr:1 row_mask:0xf bank_mask:0xf\n\t"
            "v_max_f32_dpp %1, %4, %5 wave_shr:1 row_mask:0xf bank_mask:0xf"
            : "=&v"(uA), "=&v"(uB)
            : "v"(cA), "v"(aA), "v"(cB), "v"(aB));
        uA = l0c ? aA : uA;                     // lanes 0,32: u = a (own only)
        uB = l0c ? aB : uB;
        scan_max32_x2(uA, uB);                  // dual fused prefix max
        float vA = ZoA - uA;                    // S + prefmin(e)
        float vB = ZoB - uB;
        if (first && k4 == 0 && e == 0) {       // init col = cumsum = Z - KB
          vA = ZoA - KB;
          vB = ZoB - KB;
        }
        dcurA = vA; dcurB = vB;
        if (e == 0) { rvA.x = vA; rvB.x = vB; }
        else if (e == 1) { rvA.y = vA; rvB.y = vB; }
        else if (e == 2) { rvA.z = vA; rvB.z = vB; }
        else { rvA.w = vA; rvB.w = vB; }
      }
      if (k4 == 0) { rA0 = rvA; rB0 = rvB; }
      else if (k4 == 1) { rA1 = rvA; rB1 = rvB; }
      else if (k4 == 2) { rA2 = rvA; rB2 = rvB; }
      else { rA3 = rvA; rB3 = rvB; }
    }
    if (store) {                      // one exec-mask region per tile
      if (l31) {
        float* opA = orowA + (t << 4);
        float* opB = orowB + (t << 4);
        float4 s;
        s.x = __builtin_amdgcn_sqrtf(rA0.x); s.y = __builtin_amdgcn_sqrtf(rA0.y);
        s.z = __builtin_amdgcn_sqrtf(rA0.z); s.w = __builtin_amdgcn_sqrtf(rA0.w);
        *(float4*)(opA + 0) = s;
        s.x = __builtin_amdgcn_sqrtf(rA1.x); s.y = __builtin_amdgcn_sqrtf(rA1.y);
        s.z = __builtin_amdgcn_sqrtf(rA1.z); s.w = __builtin_amdgcn_sqrtf(rA1.w);
        *(float4*)(opA + 4) = s;
        s.x = __builtin_amdgcn_sqrtf(rA2.x); s.y = __builtin_amdgcn_sqrtf(rA2.y);
        s.z = __builtin_amdgcn_sqrtf(rA2.z); s.w = __builtin_amdgcn_sqrtf(rA2.w);
        *(float4*)(opA + 8) = s;
        s.x = __builtin_amdgcn_sqrtf(rA3.x); s.y = __builtin_amdgcn_sqrtf(rA3.y);
        s.z = __builtin_amdgcn_sqrtf(rA3.z); s.w = __builtin_amdgcn_sqrtf(rA3.w);
        *(float4*)(opA + 12) = s;
        s.x = __builtin_amdgcn_sqrtf(rB0.x); s.y = __builtin_amdgcn_sqrtf(rB0.y);
        s.z = __builtin_amdgcn_sqrtf(rB0.z); s.w = __builtin_amdgcn_sqrtf(rB0.w);
        *(float4*)(opB + 0) = s;
        s.x = __builtin_amdgcn_sqrtf(rB1.x); s.y = __builtin_amdgcn_sqrtf(rB1.y);
        s.z = __builtin_amdgcn_sqrtf(rB1.z); s.w = __builtin_amdgcn_sqrtf(rB1.w);
        *(float4*)(opB + 4) = s;
        s.x = __builtin_amdgcn_sqrtf(rB2.x); s.y = __builtin_amdgcn_sqrtf(rB2.y);
        s.z = __builtin_amdgcn_sqrtf(rB2.z); s.w = __builtin_amdgcn_sqrtf(rB2.w);
        *(float4*)(opB + 8) = s;
        s.x = __builtin_amdgcn_sqrtf(rB3.x); s.y = __builtin_amdgcn_sqrtf(rB3.y);
        s.z = __builtin_amdgcn_sqrtf(rB3.z); s.w = __builtin_amdgcn_sqrtf(rB3.w);
        *(float4*)(opB + 12) = s;
      }
    }
  }
}

extern "C" void kernel_launch(void* const* d_in, const int* in_sizes, int n_in,
                              void* d_out, int out_size, void* d_ws, size_t ws_size,
                              hipStream_t stream) {
  const float* x     = (const float*)d_in[0];
  const float* patts = (const float*)d_in[1];
  const float* w     = (const float*)d_in[2];
  float* out = (float*)d_out;

  ushort_t* xA = (ushort_t*)d_ws;                                       // 2 MiB
  ushort_t* pB = (ushort_t*)((char*)d_ws + (size_t)B_ * T_ * 32 * 2);   // 128 KiB

  prep_fused<<<144, 256, 0, stream>>>(x, patts, xA, pB);
  dtw_kernel<<<B_ * (P_ / 16) * 4, 256, 0, stream>>>(xA, pB, w, out);
}